// Round 1
// baseline (587.073 us; speedup 1.0000x reference)
//
#include <hip/hip_runtime.h>

typedef unsigned short ushortT;

constexpr int B_ = 256, P_ = 32, N_ = 60;
constexpr int NE = N_ * (N_ - 1);          // 3540 edges per batch
constexpr int NETOT = B_ * NE;             // 906240 total edge rows
constexpr int ROWS = B_ * N_;              // 15360 object rows
constexpr float EPS = 1e-5f;

// ---- workspace layout (float offsets) ----
constexpr size_t F_U      = 0;                                  // ROWS*64 (bias folded in)
constexpr size_t F_V      = F_U + (size_t)ROWS * 64;            // ROWS*64
constexpr size_t F_XT     = F_V + (size_t)ROWS * 64;            // ROWS*32  xbn transposed [b][n][p]
constexpr size_t F_EBAR   = F_XT + (size_t)ROWS * 32;           // ROWS*32
constexpr size_t F_HO1    = F_EBAR + (size_t)ROWS * 32;         // ROWS*64
constexpr size_t F_HO2    = F_HO1 + (size_t)ROWS * 64;          // ROWS*64
constexpr size_t F_HO3    = F_HO2 + (size_t)ROWS * 64;          // ROWS*32
constexpr size_t F_SCALEX = F_HO3 + (size_t)ROWS * 32;          // 32
constexpr size_t F_SHIFTX = F_SCALEX + 32;                      // 32
constexpr size_t F_BN1S   = F_SHIFTX + 32;                      // B*64
constexpr size_t F_BN1Q   = F_BN1S + (size_t)B_ * 64;           // B*64
constexpr size_t F_SC1    = F_BN1Q + (size_t)B_ * 64;           // 64
constexpr size_t F_SH1    = F_SC1 + 64;
constexpr size_t F_SC2    = F_SH1 + 64;
constexpr size_t F_SH2    = F_SC2 + 64;
constexpr size_t F_SC3    = F_SH2 + 64;                         // 32
constexpr size_t F_SH3    = F_SC3 + 32;
constexpr size_t F_SCO1   = F_SH3 + 32;                         // 64
constexpr size_t F_SHO1   = F_SCO1 + 64;
constexpr size_t F_SCO2   = F_SHO1 + 64;
constexpr size_t F_SHO2   = F_SCO2 + 64;
constexpr size_t F_SCO3   = F_SHO2 + 64;                        // 32
constexpr size_t F_SHO3   = F_SCO3 + 32;
// zero-initialized (atomic accumulation) region:
constexpr size_t F_PART2  = F_SHO3 + 32;                        // 1024*128
constexpr size_t F_PART3  = F_PART2 + 1024 * 128;               // 1024*64
constexpr size_t F_SO1    = F_PART3 + 1024 * 64;                // 128
constexpr size_t F_SO2    = F_SO1 + 128;                        // 128
constexpr size_t F_SO3    = F_SO2 + 128;                        // 64
constexpr size_t F_MSET       = F_PART2;
constexpr size_t F_MSET_CNT   = (F_SO3 + 64) - F_PART2;
// bf16 (ushort) regions:
constexpr size_t F_H2     = ((F_SO3 + 64) + 3) & ~(size_t)3;    // NETOT*64 ushorts
constexpr size_t F_H3     = F_H2 + (size_t)NETOT * 32;          // NETOT*32 ushorts
constexpr size_t F_TOTAL  = F_H3 + (size_t)NETOT * 16;          // total floats

static __device__ __forceinline__ ushortT f2bf(float f) {
    unsigned int u = __float_as_uint(f);
    u += 0x7fffu + ((u >> 16) & 1u);
    return (ushortT)(u >> 16);
}
static __device__ __forceinline__ float bf2f(ushortT s) {
    return __uint_as_float(((unsigned int)s) << 16);
}

struct alignas(16) US8 { ushortT u[8]; };

// ---- K0: input BN stats per feature p over (B,N) ----
__global__ __launch_bounds__(256) void k0_inbn(const float* __restrict__ x,
                                               const float* __restrict__ g,
                                               const float* __restrict__ bt,
                                               float* __restrict__ ws) {
    int p = blockIdx.x;
    float s = 0.f, q = 0.f;
    for (int idx = threadIdx.x; idx < B_ * N_; idx += 256) {
        int b = idx / N_, n = idx - b * N_;
        float v = x[(size_t)(b * P_ + p) * N_ + n];
        s += v; q += v * v;
    }
    for (int o = 32; o > 0; o >>= 1) { s += __shfl_down(s, o); q += __shfl_down(q, o); }
    __shared__ float rs[4], rq[4];
    int wid = threadIdx.x >> 6, lane = threadIdx.x & 63;
    if (lane == 0) { rs[wid] = s; rq[wid] = q; }
    __syncthreads();
    if (threadIdx.x == 0) {
        s = rs[0] + rs[1] + rs[2] + rs[3];
        q = rq[0] + rq[1] + rq[2] + rq[3];
        float inv = 1.f / (float)(B_ * N_);
        float mean = s * inv;
        float var = q * inv - mean * mean;
        float sc = g[p] * rsqrtf(var + EPS);
        ws[F_SCALEX + p] = sc;
        ws[F_SHIFTX + p] = bt[p] - mean * sc;
    }
}

// ---- K1: U = xbn·Wrecv^T + b1, V = xbn·Wsend^T; also write xt (xbn transposed) ----
__global__ __launch_bounds__(256) void k1_uv(const float* __restrict__ x,
                                             const float* __restrict__ w1,
                                             const float* __restrict__ b1,
                                             float* __restrict__ ws) {
    int b = blockIdx.x;
    __shared__ float xs[P_ * N_];       // xbn[p][n]
    __shared__ float w1t[64 * 65];      // w1t[c][k] = w1[k*64+c], pitch 65
    const float* sX = ws + F_SCALEX;
    const float* tX = ws + F_SHIFTX;
    for (int idx = threadIdx.x; idx < P_ * N_; idx += 256) {
        int p = idx / N_, n = idx - p * N_;
        xs[idx] = sX[p] * x[(size_t)(b * P_ + p) * N_ + n] + tX[p];
    }
    for (int idx = threadIdx.x; idx < 64 * 64; idx += 256) {
        int k = idx >> 6, c = idx & 63;
        w1t[c * 65 + k] = w1[idx];
    }
    __syncthreads();
    for (int idx = threadIdx.x; idx < N_ * P_; idx += 256) {
        int n = idx / P_, p = idx - n * P_;
        ws[F_XT + (size_t)(b * N_ + n) * P_ + p] = xs[p * N_ + n];
    }
    for (int idx = threadIdx.x; idx < N_ * 64; idx += 256) {
        int n = idx >> 6, k = idx & 63;
        float u = b1[k], v = 0.f;
        #pragma unroll
        for (int p = 0; p < P_; ++p) {
            float xv = xs[p * N_ + n];
            u += xv * w1t[p * 65 + k];
            v += xv * w1t[(P_ + p) * 65 + k];
        }
        ws[F_U + (size_t)(b * N_ + n) * 64 + k] = u;
        ws[F_V + (size_t)(b * N_ + n) * 64 + k] = v;
    }
}

// ---- K2: per-batch closed-form BN1 partial stats ----
__global__ __launch_bounds__(64) void k2_bn1(float* __restrict__ ws) {
    int b = blockIdx.x, k = threadIdx.x;
    const float* Up = ws + F_U + (size_t)b * N_ * 64;
    const float* Vp = ws + F_V + (size_t)b * N_ * 64;
    float su = 0, sv = 0, suu = 0, svv = 0, suv = 0;
    for (int n = 0; n < N_; ++n) {
        float u = Up[n * 64 + k], v = Vp[n * 64 + k];
        su += u; sv += v; suu += u * u; svv += v * v; suv += u * v;
    }
    ws[F_BN1S + b * 64 + k] = 59.f * (su + sv);
    ws[F_BN1Q + b * 64 + k] = 59.f * (suu + svv) + 2.f * (su * sv - suv);
}

// ---- K3: finalize BN1 ----
__global__ __launch_bounds__(64) void k3_fin1(const float* __restrict__ g,
                                              const float* __restrict__ be,
                                              float* __restrict__ ws) {
    int k = threadIdx.x;
    float S = 0, Q = 0;
    for (int b = 0; b < B_; ++b) { S += ws[F_BN1S + b * 64 + k]; Q += ws[F_BN1Q + b * 64 + k]; }
    float inv = 1.f / (float)NETOT;
    float mean = S * inv;
    float var = Q * inv - mean * mean;
    float sc = g[k] * rsqrtf(var + EPS);
    ws[F_SC1 + k] = sc;
    ws[F_SH1 + k] = be[k] - mean * sc;
}

// ---- K4: edge layer 1->2: e1 = relu(bn1(U_i+V_j)); h2 = e1·W2^T + b2 (store bf16, stats) ----
__global__ __launch_bounds__(64) void k4_edge1(const float* __restrict__ w2,
                                               const float* __restrict__ b2,
                                               float* __restrict__ ws) {
    __shared__ __align__(16) float e1T[64 * 68];   // [k][e] pitch 68
    __shared__ __align__(16) float w2T[64 * 68];   // [k][f] pitch 68
    const int t = threadIdx.x;
    const int e0 = blockIdx.x * 64;
    for (int idx = t; idx < 4096; idx += 64) {
        int f = idx >> 6, k = idx & 63;
        w2T[k * 68 + f] = w2[idx];
    }
    const float sc1 = ws[F_SC1 + t];
    const float sh1 = ws[F_SH1 + t];
    const float* __restrict__ Ub = ws + F_U;
    const float* __restrict__ Vb = ws + F_V;
    #pragma unroll 4
    for (int e = 0; e < 64; ++e) {
        int eg = e0 + e;
        int b = eg / NE;
        int r = eg - b * NE;
        int i = r / 59;
        int rr = r - i * 59;
        int j = rr + (rr >= i ? 1 : 0);
        float u = Ub[(size_t)(b * N_ + i) * 64 + t];
        float v = Vb[(size_t)(b * N_ + j) * 64 + t];
        e1T[t * 68 + e] = fmaxf(0.f, sc1 * (u + v) + sh1);
    }
    __syncthreads();
    const int te = t & 7, tf = t >> 3;
    const int f0 = tf * 8;
    float acc[8][8];
    #pragma unroll
    for (int a = 0; a < 8; ++a)
        #pragma unroll
        for (int c = 0; c < 8; ++c) acc[a][c] = 0.f;
    const float* ept = e1T + te * 8;
    const float* wpt = w2T + f0;
    #pragma unroll 8
    for (int k = 0; k < 64; ++k) {
        float4 ea = *reinterpret_cast<const float4*>(ept + k * 68);
        float4 eb = *reinterpret_cast<const float4*>(ept + k * 68 + 4);
        float4 wa = *reinterpret_cast<const float4*>(wpt + k * 68);
        float4 wb = *reinterpret_cast<const float4*>(wpt + k * 68 + 4);
        float ev[8] = {ea.x, ea.y, ea.z, ea.w, eb.x, eb.y, eb.z, eb.w};
        float wv[8] = {wa.x, wa.y, wa.z, wa.w, wb.x, wb.y, wb.z, wb.w};
        #pragma unroll
        for (int a = 0; a < 8; ++a)
            #pragma unroll
            for (int c = 0; c < 8; ++c) acc[a][c] += ev[a] * wv[c];
    }
    float bv[8];
    #pragma unroll
    for (int c = 0; c < 8; ++c) bv[c] = b2[f0 + c];
    ushortT* __restrict__ h2p = reinterpret_cast<ushortT*>(ws + F_H2);
    float lsum[8], lsq[8];
    #pragma unroll
    for (int c = 0; c < 8; ++c) { lsum[c] = 0.f; lsq[c] = 0.f; }
    #pragma unroll
    for (int a = 0; a < 8; ++a) {
        int eg = e0 + te * 8 + a;
        US8 pk;
        #pragma unroll
        for (int c = 0; c < 8; ++c) {
            float hv = acc[a][c] + bv[c];
            lsum[c] += hv; lsq[c] += hv * hv;
            pk.u[c] = f2bf(hv);
        }
        *reinterpret_cast<US8*>(h2p + (size_t)eg * 64 + f0) = pk;
    }
    #pragma unroll
    for (int o = 4; o >= 1; o >>= 1) {
        #pragma unroll
        for (int c = 0; c < 8; ++c) {
            lsum[c] += __shfl_down(lsum[c], o, 8);
            lsq[c]  += __shfl_down(lsq[c], o, 8);
        }
    }
    if (te == 0) {
        float* pbuf = ws + F_PART2 + (size_t)(blockIdx.x & 1023) * 128;
        #pragma unroll
        for (int c = 0; c < 8; ++c) {
            atomicAdd(pbuf + f0 + c, lsum[c]);
            atomicAdd(pbuf + 64 + f0 + c, lsq[c]);
        }
    }
}

// ---- K5: finalize BN2 ----
__global__ __launch_bounds__(128) void k5_fin2(const float* __restrict__ g,
                                               const float* __restrict__ be,
                                               float* __restrict__ ws) {
    int s = threadIdx.x;
    const float* part = ws + F_PART2;
    float acc = 0.f;
    for (int r = 0; r < 1024; ++r) acc += part[(size_t)r * 128 + s];
    __shared__ float tot[128];
    tot[s] = acc;
    __syncthreads();
    if (s < 64) {
        float inv = 1.f / (float)NETOT;
        float mean = tot[s] * inv;
        float var = tot[64 + s] * inv - mean * mean;
        float sc = g[s] * rsqrtf(var + EPS);
        ws[F_SC2 + s] = sc;
        ws[F_SH2 + s] = be[s] - mean * sc;
    }
}

// ---- K6: edge layer 2->3: e2 = relu(bn2(h2)); h3 = e2·W3^T + b3 (store bf16, stats) ----
__global__ __launch_bounds__(64) void k6_edge2(const float* __restrict__ w3,
                                               const float* __restrict__ b3,
                                               float* __restrict__ ws) {
    __shared__ __align__(16) float e2T[64 * 132];  // [k][e] pitch 132 (128 edges)
    __shared__ __align__(16) float w3T[64 * 36];   // [k][f] pitch 36 (32 f)
    const int t = threadIdx.x;
    const int e0 = blockIdx.x * 128;
    for (int idx = t; idx < 2048; idx += 64) {
        int f = idx >> 6, k = idx & 63;
        w3T[k * 36 + f] = w3[idx];
    }
    const float sc2 = ws[F_SC2 + t];
    const float sh2 = ws[F_SH2 + t];
    const ushortT* __restrict__ h2p = reinterpret_cast<const ushortT*>(ws + F_H2);
    #pragma unroll 4
    for (int e = 0; e < 128; ++e) {
        float hv = bf2f(h2p[(size_t)(e0 + e) * 64 + t]);
        e2T[t * 132 + e] = fmaxf(0.f, sc2 * hv + sh2);
    }
    __syncthreads();
    const int te = t & 15, tf = t >> 4;
    const int f0 = tf * 8;
    float acc[8][8];
    #pragma unroll
    for (int a = 0; a < 8; ++a)
        #pragma unroll
        for (int c = 0; c < 8; ++c) acc[a][c] = 0.f;
    const float* ept = e2T + te * 8;
    const float* wpt = w3T + f0;
    #pragma unroll 8
    for (int k = 0; k < 64; ++k) {
        float4 ea = *reinterpret_cast<const float4*>(ept + k * 132);
        float4 eb = *reinterpret_cast<const float4*>(ept + k * 132 + 4);
        float4 wa = *reinterpret_cast<const float4*>(wpt + k * 36);
        float4 wb = *reinterpret_cast<const float4*>(wpt + k * 36 + 4);
        float ev[8] = {ea.x, ea.y, ea.z, ea.w, eb.x, eb.y, eb.z, eb.w};
        float wv[8] = {wa.x, wa.y, wa.z, wa.w, wb.x, wb.y, wb.z, wb.w};
        #pragma unroll
        for (int a = 0; a < 8; ++a)
            #pragma unroll
            for (int c = 0; c < 8; ++c) acc[a][c] += ev[a] * wv[c];
    }
    float bv[8];
    #pragma unroll
    for (int c = 0; c < 8; ++c) bv[c] = b3[f0 + c];
    ushortT* __restrict__ h3p = reinterpret_cast<ushortT*>(ws + F_H3);
    float lsum[8], lsq[8];
    #pragma unroll
    for (int c = 0; c < 8; ++c) { lsum[c] = 0.f; lsq[c] = 0.f; }
    #pragma unroll
    for (int a = 0; a < 8; ++a) {
        int eg = e0 + te * 8 + a;
        US8 pk;
        #pragma unroll
        for (int c = 0; c < 8; ++c) {
            float hv = acc[a][c] + bv[c];
            lsum[c] += hv; lsq[c] += hv * hv;
            pk.u[c] = f2bf(hv);
        }
        *reinterpret_cast<US8*>(h3p + (size_t)eg * 32 + f0) = pk;
    }
    #pragma unroll
    for (int o = 8; o >= 1; o >>= 1) {
        #pragma unroll
        for (int c = 0; c < 8; ++c) {
            lsum[c] += __shfl_down(lsum[c], o, 16);
            lsq[c]  += __shfl_down(lsq[c], o, 16);
        }
    }
    if (te == 0) {
        float* pbuf = ws + F_PART3 + (size_t)(blockIdx.x & 1023) * 64;
        #pragma unroll
        for (int c = 0; c < 8; ++c) {
            atomicAdd(pbuf + f0 + c, lsum[c]);
            atomicAdd(pbuf + 32 + f0 + c, lsq[c]);
        }
    }
}

// ---- K7: finalize BN3 ----
__global__ __launch_bounds__(64) void k7_fin3(const float* __restrict__ g,
                                              const float* __restrict__ be,
                                              float* __restrict__ ws) {
    int s = threadIdx.x;
    const float* part = ws + F_PART3;
    float acc = 0.f;
    for (int r = 0; r < 1024; ++r) acc += part[(size_t)r * 64 + s];
    __shared__ float tot[64];
    tot[s] = acc;
    __syncthreads();
    if (s < 32) {
        float inv = 1.f / (float)NETOT;
        float mean = tot[s] * inv;
        float var = tot[32 + s] * inv - mean * mean;
        float sc = g[s] * rsqrtf(var + EPS);
        ws[F_SC3 + s] = sc;
        ws[F_SH3 + s] = be[s] - mean * sc;
    }
}

// ---- K8: Ebar[b,i] = sum over 59 contiguous edges of relu(bn3(h3)) ----
__global__ __launch_bounds__(64) void k8_scatter(float* __restrict__ ws) {
    int grp = blockIdx.x;                   // b*60+i
    int t = threadIdx.x;
    int f = t & 31, h = t >> 5;
    const float sc = ws[F_SC3 + f], sh = ws[F_SH3 + f];
    const ushortT* __restrict__ h3p = reinterpret_cast<const ushortT*>(ws + F_H3);
    int b = grp / N_, i = grp - b * N_;
    size_t base = ((size_t)b * NE + (size_t)i * 59) * 32;
    float acc = 0.f;
    for (int q = h; q < 59; q += 2) {
        float hv = bf2f(h3p[base + (size_t)q * 32 + f]);
        acc += fmaxf(0.f, sc * hv + sh);
    }
    acc += __shfl_down(acc, 32);
    if (h == 0) ws[F_EBAR + (size_t)grp * 32 + f] = acc;
}

// ---- object-path linear (+optional input bn-relu), stats accumulated ----
template <int OUT>
__global__ __launch_bounds__(256) void k_obj(const float* __restrict__ srcA,
                                             const float* __restrict__ srcB,
                                             const float* __restrict__ actSc,
                                             const float* __restrict__ actSh,
                                             const float* __restrict__ W,
                                             const float* __restrict__ bias,
                                             float* __restrict__ outp,
                                             float* __restrict__ statBuf) {
    constexpr int TRN = (OUT == 64) ? 16 : 32;
    constexpr int RB = 4 * TRN;       // rows per block
    constexpr int SP = RB + 4;        // sinT pitch
    constexpr int WP = OUT + 4;       // swt pitch
    __shared__ __align__(16) float sinT[64 * SP];   // [k][r]
    __shared__ __align__(16) float swt[64 * WP];    // [k][o]
    const int t = threadIdx.x;
    const int row0 = blockIdx.x * RB;
    for (int idx = t; idx < RB * 64; idx += 256) {
        int r = idx % RB, k = idx / RB;
        float v;
        if (srcB) {
            v = (k < 32) ? srcA[(size_t)(row0 + r) * 32 + k]
                         : srcB[(size_t)(row0 + r) * 32 + (k - 32)];
        } else {
            v = srcA[(size_t)(row0 + r) * 64 + k];
        }
        if (actSc) v = fmaxf(0.f, actSc[k] * v + actSh[k]);
        sinT[k * SP + r] = v;
    }
    for (int idx = t; idx < OUT * 64; idx += 256) {
        int o = idx >> 6, k = idx & 63;
        swt[k * WP + o] = W[idx];
    }
    __syncthreads();
    const int tr = t % TRN, to = t / TRN;
    const int r0 = tr * 4, o0 = to * 4;
    float acc[4][4];
    #pragma unroll
    for (int a = 0; a < 4; ++a)
        #pragma unroll
        for (int c = 0; c < 4; ++c) acc[a][c] = 0.f;
    #pragma unroll 8
    for (int k = 0; k < 64; ++k) {
        float4 a4 = *reinterpret_cast<const float4*>(sinT + k * SP + r0);
        float4 w4 = *reinterpret_cast<const float4*>(swt + k * WP + o0);
        float av[4] = {a4.x, a4.y, a4.z, a4.w};
        float wv[4] = {w4.x, w4.y, w4.z, w4.w};
        #pragma unroll
        for (int a = 0; a < 4; ++a)
            #pragma unroll
            for (int c = 0; c < 4; ++c) acc[a][c] += av[a] * wv[c];
    }
    float bv[4];
    #pragma unroll
    for (int c = 0; c < 4; ++c) bv[c] = bias[o0 + c];
    float lsum[4] = {0.f, 0.f, 0.f, 0.f}, lsq[4] = {0.f, 0.f, 0.f, 0.f};
    #pragma unroll
    for (int a = 0; a < 4; ++a) {
        float4 res;
        float rv[4];
        #pragma unroll
        for (int c = 0; c < 4; ++c) {
            rv[c] = acc[a][c] + bv[c];
            lsum[c] += rv[c]; lsq[c] += rv[c] * rv[c];
        }
        res.x = rv[0]; res.y = rv[1]; res.z = rv[2]; res.w = rv[3];
        *reinterpret_cast<float4*>(outp + (size_t)(row0 + r0 + a) * OUT + o0) = res;
    }
    #pragma unroll
    for (int o = TRN / 2; o >= 1; o >>= 1) {
        #pragma unroll
        for (int c = 0; c < 4; ++c) {
            lsum[c] += __shfl_down(lsum[c], o, TRN);
            lsq[c]  += __shfl_down(lsq[c], o, TRN);
        }
    }
    if (tr == 0) {
        #pragma unroll
        for (int c = 0; c < 4; ++c) {
            atomicAdd(statBuf + o0 + c, lsum[c]);
            atomicAdd(statBuf + OUT + o0 + c, lsq[c]);
        }
    }
}

template <int OUTK>
__global__ void k_finO(const float* __restrict__ statBuf, const float* __restrict__ g,
                       const float* __restrict__ be, float* __restrict__ scO,
                       float* __restrict__ shO) {
    int k = threadIdx.x;
    if (k < OUTK) {
        float inv = 1.f / (float)ROWS;
        float mean = statBuf[k] * inv;
        float var = statBuf[OUTK + k] * inv - mean * mean;
        float sc = g[k] * rsqrtf(var + EPS);
        scO[k] = sc;
        shO[k] = be[k] - mean * sc;
    }
}

// ---- K15: relu(bn(ho3)), pool over n, fc ----
__global__ __launch_bounds__(64) void k15_final(const float* __restrict__ fcw,
                                                const float* __restrict__ fcb,
                                                float* __restrict__ ws,
                                                float* __restrict__ out) {
    int b = blockIdx.x, t = threadIdx.x;
    int f = t & 31, h = t >> 5;
    float sc = ws[F_SCO3 + f], sh = ws[F_SHO3 + f];
    float acc = 0.f;
    for (int n = h; n < N_; n += 2) {
        float v = ws[F_HO3 + (size_t)(b * N_ + n) * 32 + f];
        acc += fmaxf(0.f, sc * v + sh);
    }
    acc += __shfl_down(acc, 32);
    float p0 = acc * fcw[f];
    float p1 = acc * fcw[32 + f];
    #pragma unroll
    for (int o = 16; o >= 1; o >>= 1) {
        p0 += __shfl_xor(p0, o);
        p1 += __shfl_xor(p1, o);
    }
    if (t == 0) {
        out[b * 2 + 0] = p0 + fcb[0];
        out[b * 2 + 1] = p1 + fcb[1];
    }
}

extern "C" void kernel_launch(void* const* d_in, const int* in_sizes, int n_in,
                              void* d_out, int out_size, void* d_ws, size_t ws_size,
                              hipStream_t stream) {
    const float* x      = (const float*)d_in[0];
    const float* bnx_g  = (const float*)d_in[1];
    const float* bnx_b  = (const float*)d_in[2];
    const float* fr1_w  = (const float*)d_in[3];
    const float* fr1_b  = (const float*)d_in[4];
    const float* fr1_g  = (const float*)d_in[5];
    const float* fr1_be = (const float*)d_in[6];
    const float* fr2_w  = (const float*)d_in[7];
    const float* fr2_b  = (const float*)d_in[8];
    const float* fr2_g  = (const float*)d_in[9];
    const float* fr2_be = (const float*)d_in[10];
    const float* fr3_w  = (const float*)d_in[11];
    const float* fr3_b  = (const float*)d_in[12];
    const float* fr3_g  = (const float*)d_in[13];
    const float* fr3_be = (const float*)d_in[14];
    const float* fo1_w  = (const float*)d_in[15];
    const float* fo1_b  = (const float*)d_in[16];
    const float* fo1_g  = (const float*)d_in[17];
    const float* fo1_be = (const float*)d_in[18];
    const float* fo2_w  = (const float*)d_in[19];
    const float* fo2_b  = (const float*)d_in[20];
    const float* fo2_g  = (const float*)d_in[21];
    const float* fo2_be = (const float*)d_in[22];
    const float* fo3_w  = (const float*)d_in[23];
    const float* fo3_b  = (const float*)d_in[24];
    const float* fo3_g  = (const float*)d_in[25];
    const float* fo3_be = (const float*)d_in[26];
    const float* fc_w   = (const float*)d_in[27];
    const float* fc_b   = (const float*)d_in[28];

    float* ws = (float*)d_ws;
    float* out = (float*)d_out;
    if (ws_size < F_TOTAL * sizeof(float)) return;   // leaves out wrong -> visible failure signature

    hipMemsetAsync(ws + F_MSET, 0, F_MSET_CNT * sizeof(float), stream);
    k0_inbn<<<P_, 256, 0, stream>>>(x, bnx_g, bnx_b, ws);
    k1_uv<<<B_, 256, 0, stream>>>(x, fr1_w, fr1_b, ws);
    k2_bn1<<<B_, 64, 0, stream>>>(ws);
    k3_fin1<<<1, 64, 0, stream>>>(fr1_g, fr1_be, ws);
    k4_edge1<<<NETOT / 64, 64, 0, stream>>>(fr2_w, fr2_b, ws);
    k5_fin2<<<1, 128, 0, stream>>>(fr2_g, fr2_be, ws);
    k6_edge2<<<NETOT / 128, 64, 0, stream>>>(fr3_w, fr3_b, ws);
    k7_fin3<<<1, 64, 0, stream>>>(fr3_g, fr3_be, ws);
    k8_scatter<<<ROWS, 64, 0, stream>>>(ws);
    k_obj<64><<<ROWS / 64, 256, 0, stream>>>(ws + F_XT, ws + F_EBAR, nullptr, nullptr,
                                             fo1_w, fo1_b, ws + F_HO1, ws + F_SO1);
    k_finO<64><<<1, 64, 0, stream>>>(ws + F_SO1, fo1_g, fo1_be, ws + F_SCO1, ws + F_SHO1);
    k_obj<64><<<ROWS / 64, 256, 0, stream>>>(ws + F_HO1, nullptr, ws + F_SCO1, ws + F_SHO1,
                                             fo2_w, fo2_b, ws + F_HO2, ws + F_SO2);
    k_finO<64><<<1, 64, 0, stream>>>(ws + F_SO2, fo2_g, fo2_be, ws + F_SCO2, ws + F_SHO2);
    k_obj<32><<<ROWS / 128, 256, 0, stream>>>(ws + F_HO2, nullptr, ws + F_SCO2, ws + F_SHO2,
                                              fo3_w, fo3_b, ws + F_HO3, ws + F_SO3);
    k_finO<32><<<1, 32, 0, stream>>>(ws + F_SO3, fo3_g, fo3_be, ws + F_SCO3, ws + F_SHO3);
    k15_final<<<B_, 64, 0, stream>>>(fc_w, fc_b, ws, out);
}

// Round 2
// 501.399 us; speedup vs baseline: 1.1709x; 1.1709x over previous
//
#include <hip/hip_runtime.h>

typedef unsigned short ushortT;
typedef __attribute__((ext_vector_type(8))) short bf16x8;
typedef __attribute__((ext_vector_type(4))) float f32x4;

constexpr int B_ = 256, P_ = 32, N_ = 60;
constexpr int NE = N_ * (N_ - 1);          // 3540 edges per batch
constexpr int NETOT = B_ * NE;             // 906240 total edge rows
constexpr int ROWS = B_ * N_;              // 15360 object rows
constexpr float EPS = 1e-5f;

// ---- workspace layout (float offsets) ----
constexpr size_t F_U      = 0;                                  // ROWS*64 (bias folded in)
constexpr size_t F_V      = F_U + (size_t)ROWS * 64;            // ROWS*64
constexpr size_t F_XT     = F_V + (size_t)ROWS * 64;            // ROWS*32 xbn transposed
constexpr size_t F_EBAR   = F_XT + (size_t)ROWS * 32;           // ROWS*32
constexpr size_t F_HO1    = F_EBAR + (size_t)ROWS * 32;         // ROWS*64
constexpr size_t F_HO2    = F_HO1 + (size_t)ROWS * 64;          // ROWS*64
constexpr size_t F_HO3    = F_HO2 + (size_t)ROWS * 64;          // ROWS*32
constexpr size_t F_SCALEX = F_HO3 + (size_t)ROWS * 32;          // 32
constexpr size_t F_SHIFTX = F_SCALEX + 32;                      // 32
constexpr size_t F_BN1S   = F_SHIFTX + 32;                      // B*64
constexpr size_t F_BN1Q   = F_BN1S + (size_t)B_ * 64;           // B*64
constexpr size_t F_SC1    = F_BN1Q + (size_t)B_ * 64;           // 64
constexpr size_t F_SH1    = F_SC1 + 64;
constexpr size_t F_SC2    = F_SH1 + 64;
constexpr size_t F_SH2    = F_SC2 + 64;
constexpr size_t F_SC3    = F_SH2 + 64;                         // 32
constexpr size_t F_SH3    = F_SC3 + 32;
constexpr size_t F_SCO1   = F_SH3 + 32;                         // 64
constexpr size_t F_SHO1   = F_SCO1 + 64;
constexpr size_t F_SCO2   = F_SHO1 + 64;
constexpr size_t F_SHO2   = F_SCO2 + 64;
constexpr size_t F_SCO3   = F_SHO2 + 64;                        // 32
constexpr size_t F_SHO3   = F_SCO3 + 32;
constexpr size_t F_W2F    = F_SHO3 + 32;                        // 2048 floats = 4096 bf16 frags
constexpr size_t F_W3F    = F_W2F + 2048;                       // 1024 floats = 2048 bf16 frags
// zero-initialized (atomic accumulation) region:
constexpr size_t F_PART2  = F_W3F + 1024;                       // 1024*128
constexpr size_t F_PART3  = F_PART2 + 1024 * 128;               // 1024*64
constexpr size_t F_SO1    = F_PART3 + 1024 * 64;                // 128
constexpr size_t F_SO2    = F_SO1 + 128;                        // 128
constexpr size_t F_SO3    = F_SO2 + 128;                        // 64
constexpr size_t F_END    = F_SO3 + 64;
constexpr size_t F_MSET     = F_PART2;
constexpr size_t F_MSET_CNT = F_END - F_PART2;
constexpr size_t F_TOTAL  = F_END;

static __device__ __forceinline__ ushortT f2bf(float f) {
    unsigned int u = __float_as_uint(f);
    u += 0x7fffu + ((u >> 16) & 1u);
    return (ushortT)(u >> 16);
}
static __device__ __forceinline__ unsigned int packbf(float lo, float hi) {
    return (unsigned int)f2bf(lo) | ((unsigned int)f2bf(hi) << 16);
}

// ---- K0: input BN stats per feature p over (B,N) ----
__global__ __launch_bounds__(256) void k0_inbn(const float* __restrict__ x,
                                               const float* __restrict__ g,
                                               const float* __restrict__ bt,
                                               float* __restrict__ ws) {
    int p = blockIdx.x;
    float s = 0.f, q = 0.f;
    for (int idx = threadIdx.x; idx < B_ * N_; idx += 256) {
        int b = idx / N_, n = idx - b * N_;
        float v = x[(size_t)(b * P_ + p) * N_ + n];
        s += v; q += v * v;
    }
    for (int o = 32; o > 0; o >>= 1) { s += __shfl_down(s, o); q += __shfl_down(q, o); }
    __shared__ float rs[4], rq[4];
    int wid = threadIdx.x >> 6, lane = threadIdx.x & 63;
    if (lane == 0) { rs[wid] = s; rq[wid] = q; }
    __syncthreads();
    if (threadIdx.x == 0) {
        s = rs[0] + rs[1] + rs[2] + rs[3];
        q = rq[0] + rq[1] + rq[2] + rq[3];
        float inv = 1.f / (float)(B_ * N_);
        float mean = s * inv;
        float var = q * inv - mean * mean;
        float sc = g[p] * rsqrtf(var + EPS);
        ws[F_SCALEX + p] = sc;
        ws[F_SHIFTX + p] = bt[p] - mean * sc;
    }
}

// ---- KW: convert W2 (64x64), W3 (32x64) to bf16 MFMA fragment layout ----
// frag chunk (tile, kstep s, lane l): value b -> W[(tile*16 + l%16)*64 + s*32 + (l/16)*8 + b]
__global__ __launch_bounds__(256) void kW(const float* __restrict__ w2,
                                          const float* __restrict__ w3,
                                          float* __restrict__ ws) {
    int t = threadIdx.x;
    ushortT* w2f = reinterpret_cast<ushortT*>(ws + F_W2F);
    ushortT* w3f = reinterpret_cast<ushortT*>(ws + F_W3F);
    for (int c = t; c < 512; c += 256) {
        int l = c & 63, s = (c >> 6) & 1, mu = c >> 7;
        int f = mu * 16 + (l & 15);
        int k0 = s * 32 + ((l >> 4) << 3);
        const float* src = w2 + (size_t)f * 64 + k0;
        unsigned int pk[4];
        #pragma unroll
        for (int q = 0; q < 4; ++q) pk[q] = packbf(src[2 * q], src[2 * q + 1]);
        *reinterpret_cast<uint4*>(&w2f[(size_t)c * 8]) = *reinterpret_cast<uint4*>(pk);
    }
    if (t < 256) {
        int c = t;
        int l = c & 63, s = (c >> 6) & 1, mu = (c >> 7) & 1;
        int f = mu * 16 + (l & 15);
        int k0 = s * 32 + ((l >> 4) << 3);
        const float* src = w3 + (size_t)f * 64 + k0;
        unsigned int pk[4];
        #pragma unroll
        for (int q = 0; q < 4; ++q) pk[q] = packbf(src[2 * q], src[2 * q + 1]);
        *reinterpret_cast<uint4*>(&w3f[(size_t)c * 8]) = *reinterpret_cast<uint4*>(pk);
    }
}

// ---- K1: U = xbn·Wrecv^T + b1, V = xbn·Wsend^T; also write xt ----
__global__ __launch_bounds__(256) void k1_uv(const float* __restrict__ x,
                                             const float* __restrict__ w1,
                                             const float* __restrict__ b1,
                                             float* __restrict__ ws) {
    int b = blockIdx.x;
    __shared__ float xs[P_ * N_];
    __shared__ float w1t[64 * 65];
    const float* sX = ws + F_SCALEX;
    const float* tX = ws + F_SHIFTX;
    for (int idx = threadIdx.x; idx < P_ * N_; idx += 256) {
        int p = idx / N_, n = idx - p * N_;
        xs[idx] = sX[p] * x[(size_t)(b * P_ + p) * N_ + n] + tX[p];
    }
    for (int idx = threadIdx.x; idx < 64 * 64; idx += 256) {
        int k = idx >> 6, c = idx & 63;
        w1t[c * 65 + k] = w1[idx];
    }
    __syncthreads();
    for (int idx = threadIdx.x; idx < N_ * P_; idx += 256) {
        int n = idx / P_, p = idx - n * P_;
        ws[F_XT + (size_t)(b * N_ + n) * P_ + p] = xs[p * N_ + n];
    }
    for (int idx = threadIdx.x; idx < N_ * 64; idx += 256) {
        int n = idx >> 6, k = idx & 63;
        float u = b1[k], v = 0.f;
        #pragma unroll
        for (int p = 0; p < P_; ++p) {
            float xv = xs[p * N_ + n];
            u += xv * w1t[p * 65 + k];
            v += xv * w1t[(P_ + p) * 65 + k];
        }
        ws[F_U + (size_t)(b * N_ + n) * 64 + k] = u;
        ws[F_V + (size_t)(b * N_ + n) * 64 + k] = v;
    }
}

// ---- K2: per-batch closed-form BN1 partial stats ----
__global__ __launch_bounds__(64) void k2_bn1(float* __restrict__ ws) {
    int b = blockIdx.x, k = threadIdx.x;
    const float* Up = ws + F_U + (size_t)b * N_ * 64;
    const float* Vp = ws + F_V + (size_t)b * N_ * 64;
    float su = 0, sv = 0, suu = 0, svv = 0, suv = 0;
    for (int n = 0; n < N_; ++n) {
        float u = Up[n * 64 + k], v = Vp[n * 64 + k];
        su += u; sv += v; suu += u * u; svv += v * v; suv += u * v;
    }
    ws[F_BN1S + b * 64 + k] = 59.f * (su + sv);
    ws[F_BN1Q + b * 64 + k] = 59.f * (suu + svv) + 2.f * (su * sv - suv);
}

// ---- K3: finalize BN1 ----
__global__ __launch_bounds__(64) void k3_fin1(const float* __restrict__ g,
                                              const float* __restrict__ be,
                                              float* __restrict__ ws) {
    int k = threadIdx.x;
    float S = 0, Q = 0;
    for (int b = 0; b < B_; ++b) { S += ws[F_BN1S + b * 64 + k]; Q += ws[F_BN1Q + b * 64 + k]; }
    float inv = 1.f / (float)NETOT;
    float mean = S * inv;
    float var = Q * inv - mean * mean;
    float sc = g[k] * rsqrtf(var + EPS);
    ws[F_SC1 + k] = sc;
    ws[F_SH1 + k] = be[k] - mean * sc;
}

// ---- KEDGE<STAGE>: one (b,i) group (59 edges padded to 64) per block, 4 waves ----
// STAGE 1: h2 stats -> PART2.  STAGE 2: recompute h2, bn2relu, h3 stats -> PART3.
// STAGE 3: recompute all, bn3relu, segment-sum -> EBAR.
template <int STAGE>
__global__ __launch_bounds__(256) void kedge(const float* __restrict__ b2,
                                             const float* __restrict__ b3,
                                             float* __restrict__ ws) {
    __shared__ __align__(16) ushortT e1f[512 * 8];   // e1 fragments (8 KB)
    __shared__ __align__(16) ushortT e2f[512 * 8];   // e2 fragments (8 KB)
    __shared__ float red[4][64];
    const int g = blockIdx.x;
    const int b = g / N_, i = g - b * N_;
    const int t = threadIdx.x;
    const float* __restrict__ Ur = ws + F_U + (size_t)(b * N_ + i) * 64;
    const float* __restrict__ Vbase = ws + F_V + (size_t)b * N_ * 64;

    // --- build e1 fragment tile: chunk c=(m*2+s)*64+l holds 8 bf16 of
    // e1[e = m*16 + (l&15)][k = s*32 + (l>>4)*8 + 0..7]
    for (int c = t; c < 512; c += 256) {
        int l = c & 63, s = (c >> 6) & 1, m = c >> 7;
        int e_loc = m * 16 + (l & 15);
        int k0 = s * 32 + ((l >> 4) << 3);
        bool valid = e_loc < 59;
        int j = valid ? (e_loc + (e_loc >= i)) : 0;
        const float* vp = Vbase + (size_t)j * 64 + k0;
        float uu[8], vv[8], aa[8], hh[8];
        *reinterpret_cast<float4*>(uu)     = *reinterpret_cast<const float4*>(Ur + k0);
        *reinterpret_cast<float4*>(uu + 4) = *reinterpret_cast<const float4*>(Ur + k0 + 4);
        *reinterpret_cast<float4*>(vv)     = *reinterpret_cast<const float4*>(vp);
        *reinterpret_cast<float4*>(vv + 4) = *reinterpret_cast<const float4*>(vp + 4);
        *reinterpret_cast<float4*>(aa)     = *reinterpret_cast<const float4*>(ws + F_SC1 + k0);
        *reinterpret_cast<float4*>(aa + 4) = *reinterpret_cast<const float4*>(ws + F_SC1 + k0 + 4);
        *reinterpret_cast<float4*>(hh)     = *reinterpret_cast<const float4*>(ws + F_SH1 + k0);
        *reinterpret_cast<float4*>(hh + 4) = *reinterpret_cast<const float4*>(ws + F_SH1 + k0 + 4);
        unsigned int pk[4];
        #pragma unroll
        for (int q = 0; q < 4; ++q) {
            float lo = valid ? fmaxf(0.f, aa[2 * q]     * (uu[2 * q]     + vv[2 * q])     + hh[2 * q])     : 0.f;
            float hi = valid ? fmaxf(0.f, aa[2 * q + 1] * (uu[2 * q + 1] + vv[2 * q + 1]) + hh[2 * q + 1]) : 0.f;
            pk[q] = packbf(lo, hi);
        }
        *reinterpret_cast<uint4*>(&e1f[(size_t)c * 8]) = *reinterpret_cast<uint4*>(pk);
    }
    __syncthreads();

    const int w = t >> 6, lane = t & 63;
    const int gq = lane >> 4, ln = lane & 15;
    const bf16x8* __restrict__ w2fr = reinterpret_cast<const bf16x8*>(ws + F_W2F);
    const bf16x8* __restrict__ w3fr = reinterpret_cast<const bf16x8*>(ws + F_W3F);
    const bf16x8* e1c = reinterpret_cast<const bf16x8*>(e1f);
    const bf16x8* e2c = reinterpret_cast<const bf16x8*>(e2f);
    const f32x4 zero = {0.f, 0.f, 0.f, 0.f};

    if (STAGE == 1) {
        // h2 = e1 · W2^T ; wave w owns feature tile nu=w, all 4 edge tiles
        f32x4 acc[4] = {zero, zero, zero, zero};
        #pragma unroll
        for (int s = 0; s < 2; ++s) {
            bf16x8 bw = w2fr[(w * 2 + s) * 64 + lane];
            #pragma unroll
            for (int m = 0; m < 4; ++m)
                acc[m] = __builtin_amdgcn_mfma_f32_16x16x32_bf16(
                    e1c[(m * 2 + s) * 64 + lane], bw, acc[m], 0, 0, 0);
        }
        float bb = b2[w * 16 + ln];
        float lsum = 0.f, lsq = 0.f;
        #pragma unroll
        for (int m = 0; m < 4; ++m)
            #pragma unroll
            for (int r = 0; r < 4; ++r) {
                int e_loc = m * 16 + gq * 4 + r;
                if (e_loc < 59) { float h = acc[m][r] + bb; lsum += h; lsq += h * h; }
            }
        lsum += __shfl_xor(lsum, 16); lsq += __shfl_xor(lsq, 16);
        lsum += __shfl_xor(lsum, 32); lsq += __shfl_xor(lsq, 32);
        if (lane < 16) {
            float* pb = ws + F_PART2 + (size_t)(g & 1023) * 128;
            atomicAdd(pb + w * 16 + lane, lsum);
            atomicAdd(pb + 64 + w * 16 + lane, lsq);
        }
    } else {
        // h2^T = W2 · e1^T ; wave w owns edge tile nu=w (cols), all 4 feature tiles
        f32x4 acc[4] = {zero, zero, zero, zero};
        #pragma unroll
        for (int s = 0; s < 2; ++s) {
            bf16x8 be = e1c[(w * 2 + s) * 64 + lane];
            #pragma unroll
            for (int mu = 0; mu < 4; ++mu)
                acc[mu] = __builtin_amdgcn_mfma_f32_16x16x32_bf16(
                    w2fr[(mu * 2 + s) * 64 + lane], be, acc[mu], 0, 0, 0);
        }
        // e2 = relu(bn2(h2)) in-register -> scatter into e2 fragment layout (m'=w)
        #pragma unroll
        for (int mu = 0; mu < 4; ++mu) {
            int fb = mu * 16 + gq * 4;
            float4 bb  = *reinterpret_cast<const float4*>(b2 + fb);
            float4 s2  = *reinterpret_cast<const float4*>(ws + F_SC2 + fb);
            float4 h2s = *reinterpret_cast<const float4*>(ws + F_SH2 + fb);
            float ev[4];
            ev[0] = fmaxf(0.f, s2.x * (acc[mu][0] + bb.x) + h2s.x);
            ev[1] = fmaxf(0.f, s2.y * (acc[mu][1] + bb.y) + h2s.y);
            ev[2] = fmaxf(0.f, s2.z * (acc[mu][2] + bb.z) + h2s.z);
            ev[3] = fmaxf(0.f, s2.w * (acc[mu][3] + bb.w) + h2s.w);
            int sp = mu >> 1;
            int lp = ln + ((mu & 1) << 5) + ((gq >> 1) << 4);
            int base = ((w * 2 + sp) * 64 + lp) * 8 + ((gq & 1) << 2);
            *reinterpret_cast<unsigned int*>(&e2f[base])     = packbf(ev[0], ev[1]);
            *reinterpret_cast<unsigned int*>(&e2f[base + 2]) = packbf(ev[2], ev[3]);
        }
        __syncthreads();
        // h3 = e2 · W3^T ; wave w owns its own 16 edges (m'=w), 32 features
        f32x4 acc3[2] = {zero, zero};
        #pragma unroll
        for (int s = 0; s < 2; ++s) {
            bf16x8 ae = e2c[(w * 2 + s) * 64 + lane];
            #pragma unroll
            for (int nv = 0; nv < 2; ++nv)
                acc3[nv] = __builtin_amdgcn_mfma_f32_16x16x32_bf16(
                    ae, w3fr[(nv * 2 + s) * 64 + lane], acc3[nv], 0, 0, 0);
        }
        float b3v[2] = { b3[ln], b3[16 + ln] };
        if (STAGE == 2) {
            float ls[2] = {0.f, 0.f}, lq[2] = {0.f, 0.f};
            #pragma unroll
            for (int nv = 0; nv < 2; ++nv)
                #pragma unroll
                for (int r = 0; r < 4; ++r) {
                    int e_loc = w * 16 + gq * 4 + r;
                    if (e_loc < 59) {
                        float h = acc3[nv][r] + b3v[nv];
                        ls[nv] += h; lq[nv] += h * h;
                    }
                }
            #pragma unroll
            for (int nv = 0; nv < 2; ++nv) {
                ls[nv] += __shfl_xor(ls[nv], 16); lq[nv] += __shfl_xor(lq[nv], 16);
                ls[nv] += __shfl_xor(ls[nv], 32); lq[nv] += __shfl_xor(lq[nv], 32);
            }
            if (lane < 16) {
                red[w][lane] = ls[0]; red[w][16 + lane] = ls[1];
                red[w][32 + lane] = lq[0]; red[w][48 + lane] = lq[1];
            }
            __syncthreads();
            if (t < 64) {
                float tot = red[0][t] + red[1][t] + red[2][t] + red[3][t];
                atomicAdd(ws + F_PART3 + (size_t)(g & 1023) * 64 + t, tot);
            }
        } else {
            float s3[2] = { ws[F_SC3 + ln], ws[F_SC3 + 16 + ln] };
            float t3[2] = { ws[F_SH3 + ln], ws[F_SH3 + 16 + ln] };
            float es[2] = {0.f, 0.f};
            #pragma unroll
            for (int nv = 0; nv < 2; ++nv)
                #pragma unroll
                for (int r = 0; r < 4; ++r) {
                    int e_loc = w * 16 + gq * 4 + r;
                    if (e_loc < 59)
                        es[nv] += fmaxf(0.f, s3[nv] * (acc3[nv][r] + b3v[nv]) + t3[nv]);
                }
            #pragma unroll
            for (int nv = 0; nv < 2; ++nv) {
                es[nv] += __shfl_xor(es[nv], 16);
                es[nv] += __shfl_xor(es[nv], 32);
            }
            if (lane < 16) { red[w][lane] = es[0]; red[w][16 + lane] = es[1]; }
            __syncthreads();
            if (t < 32)
                ws[F_EBAR + (size_t)g * 32 + t] = red[0][t] + red[1][t] + red[2][t] + red[3][t];
        }
    }
}

// ---- K5: finalize BN2 ----
__global__ __launch_bounds__(128) void k5_fin2(const float* __restrict__ g,
                                               const float* __restrict__ be,
                                               float* __restrict__ ws) {
    int s = threadIdx.x;
    const float* part = ws + F_PART2;
    float acc = 0.f;
    for (int r = 0; r < 1024; ++r) acc += part[(size_t)r * 128 + s];
    __shared__ float tot[128];
    tot[s] = acc;
    __syncthreads();
    if (s < 64) {
        float inv = 1.f / (float)NETOT;
        float mean = tot[s] * inv;
        float var = tot[64 + s] * inv - mean * mean;
        float sc = g[s] * rsqrtf(var + EPS);
        ws[F_SC2 + s] = sc;
        ws[F_SH2 + s] = be[s] - mean * sc;
    }
}

// ---- K7: finalize BN3 ----
__global__ __launch_bounds__(64) void k7_fin3(const float* __restrict__ g,
                                              const float* __restrict__ be,
                                              float* __restrict__ ws) {
    int s = threadIdx.x;
    const float* part = ws + F_PART3;
    float acc = 0.f;
    for (int r = 0; r < 1024; ++r) acc += part[(size_t)r * 64 + s];
    __shared__ float tot[64];
    tot[s] = acc;
    __syncthreads();
    if (s < 32) {
        float inv = 1.f / (float)NETOT;
        float mean = tot[s] * inv;
        float var = tot[32 + s] * inv - mean * mean;
        float sc = g[s] * rsqrtf(var + EPS);
        ws[F_SC3 + s] = sc;
        ws[F_SH3 + s] = be[s] - mean * sc;
    }
}

// ---- object-path linear (+optional input bn-relu), stats accumulated ----
template <int OUT>
__global__ __launch_bounds__(256) void k_obj(const float* __restrict__ srcA,
                                             const float* __restrict__ srcB,
                                             const float* __restrict__ actSc,
                                             const float* __restrict__ actSh,
                                             const float* __restrict__ W,
                                             const float* __restrict__ bias,
                                             float* __restrict__ outp,
                                             float* __restrict__ statBuf) {
    constexpr int TRN = (OUT == 64) ? 16 : 32;
    constexpr int RB = 4 * TRN;
    constexpr int SP = RB + 4;
    constexpr int WP = OUT + 4;
    __shared__ __align__(16) float sinT[64 * SP];
    __shared__ __align__(16) float swt[64 * WP];
    const int t = threadIdx.x;
    const int row0 = blockIdx.x * RB;
    for (int idx = t; idx < RB * 64; idx += 256) {
        int r = idx % RB, k = idx / RB;
        float v;
        if (srcB) {
            v = (k < 32) ? srcA[(size_t)(row0 + r) * 32 + k]
                         : srcB[(size_t)(row0 + r) * 32 + (k - 32)];
        } else {
            v = srcA[(size_t)(row0 + r) * 64 + k];
        }
        if (actSc) v = fmaxf(0.f, actSc[k] * v + actSh[k]);
        sinT[k * SP + r] = v;
    }
    for (int idx = t; idx < OUT * 64; idx += 256) {
        int o = idx >> 6, k = idx & 63;
        swt[k * WP + o] = W[idx];
    }
    __syncthreads();
    const int tr = t % TRN, to = t / TRN;
    const int r0 = tr * 4, o0 = to * 4;
    float acc[4][4];
    #pragma unroll
    for (int a = 0; a < 4; ++a)
        #pragma unroll
        for (int c = 0; c < 4; ++c) acc[a][c] = 0.f;
    #pragma unroll 8
    for (int k = 0; k < 64; ++k) {
        float4 a4 = *reinterpret_cast<const float4*>(sinT + k * SP + r0);
        float4 w4 = *reinterpret_cast<const float4*>(swt + k * WP + o0);
        float av[4] = {a4.x, a4.y, a4.z, a4.w};
        float wv[4] = {w4.x, w4.y, w4.z, w4.w};
        #pragma unroll
        for (int a = 0; a < 4; ++a)
            #pragma unroll
            for (int c = 0; c < 4; ++c) acc[a][c] += av[a] * wv[c];
    }
    float bv[4];
    #pragma unroll
    for (int c = 0; c < 4; ++c) bv[c] = bias[o0 + c];
    float lsum[4] = {0.f, 0.f, 0.f, 0.f}, lsq[4] = {0.f, 0.f, 0.f, 0.f};
    #pragma unroll
    for (int a = 0; a < 4; ++a) {
        float4 res;
        float rv[4];
        #pragma unroll
        for (int c = 0; c < 4; ++c) {
            rv[c] = acc[a][c] + bv[c];
            lsum[c] += rv[c]; lsq[c] += rv[c] * rv[c];
        }
        res.x = rv[0]; res.y = rv[1]; res.z = rv[2]; res.w = rv[3];
        *reinterpret_cast<float4*>(outp + (size_t)(row0 + r0 + a) * OUT + o0) = res;
    }
    #pragma unroll
    for (int o = TRN / 2; o >= 1; o >>= 1) {
        #pragma unroll
        for (int c = 0; c < 4; ++c) {
            lsum[c] += __shfl_down(lsum[c], o, TRN);
            lsq[c]  += __shfl_down(lsq[c], o, TRN);
        }
    }
    if (tr == 0) {
        #pragma unroll
        for (int c = 0; c < 4; ++c) {
            atomicAdd(statBuf + o0 + c, lsum[c]);
            atomicAdd(statBuf + OUT + o0 + c, lsq[c]);
        }
    }
}

template <int OUTK>
__global__ void k_finO(const float* __restrict__ statBuf, const float* __restrict__ g,
                       const float* __restrict__ be, float* __restrict__ scO,
                       float* __restrict__ shO) {
    int k = threadIdx.x;
    if (k < OUTK) {
        float inv = 1.f / (float)ROWS;
        float mean = statBuf[k] * inv;
        float var = statBuf[OUTK + k] * inv - mean * mean;
        float sc = g[k] * rsqrtf(var + EPS);
        scO[k] = sc;
        shO[k] = be[k] - mean * sc;
    }
}

// ---- K15: relu(bn(ho3)), pool over n, fc ----
__global__ __launch_bounds__(64) void k15_final(const float* __restrict__ fcw,
                                                const float* __restrict__ fcb,
                                                float* __restrict__ ws,
                                                float* __restrict__ out) {
    int b = blockIdx.x, t = threadIdx.x;
    int f = t & 31, h = t >> 5;
    float sc = ws[F_SCO3 + f], sh = ws[F_SHO3 + f];
    float acc = 0.f;
    for (int n = h; n < N_; n += 2) {
        float v = ws[F_HO3 + (size_t)(b * N_ + n) * 32 + f];
        acc += fmaxf(0.f, sc * v + sh);
    }
    acc += __shfl_down(acc, 32);
    float p0 = acc * fcw[f];
    float p1 = acc * fcw[32 + f];
    #pragma unroll
    for (int o = 16; o >= 1; o >>= 1) {
        p0 += __shfl_xor(p0, o);
        p1 += __shfl_xor(p1, o);
    }
    if (t == 0) {
        out[b * 2 + 0] = p0 + fcb[0];
        out[b * 2 + 1] = p1 + fcb[1];
    }
}

extern "C" void kernel_launch(void* const* d_in, const int* in_sizes, int n_in,
                              void* d_out, int out_size, void* d_ws, size_t ws_size,
                              hipStream_t stream) {
    const float* x      = (const float*)d_in[0];
    const float* bnx_g  = (const float*)d_in[1];
    const float* bnx_b  = (const float*)d_in[2];
    const float* fr1_w  = (const float*)d_in[3];
    const float* fr1_b  = (const float*)d_in[4];
    const float* fr1_g  = (const float*)d_in[5];
    const float* fr1_be = (const float*)d_in[6];
    const float* fr2_w  = (const float*)d_in[7];
    const float* fr2_b  = (const float*)d_in[8];
    const float* fr2_g  = (const float*)d_in[9];
    const float* fr2_be = (const float*)d_in[10];
    const float* fr3_w  = (const float*)d_in[11];
    const float* fr3_b  = (const float*)d_in[12];
    const float* fr3_g  = (const float*)d_in[13];
    const float* fr3_be = (const float*)d_in[14];
    const float* fo1_w  = (const float*)d_in[15];
    const float* fo1_b  = (const float*)d_in[16];
    const float* fo1_g  = (const float*)d_in[17];
    const float* fo1_be = (const float*)d_in[18];
    const float* fo2_w  = (const float*)d_in[19];
    const float* fo2_b  = (const float*)d_in[20];
    const float* fo2_g  = (const float*)d_in[21];
    const float* fo2_be = (const float*)d_in[22];
    const float* fo3_w  = (const float*)d_in[23];
    const float* fo3_b  = (const float*)d_in[24];
    const float* fo3_g  = (const float*)d_in[25];
    const float* fo3_be = (const float*)d_in[26];
    const float* fc_w   = (const float*)d_in[27];
    const float* fc_b   = (const float*)d_in[28];

    float* ws = (float*)d_ws;
    float* out = (float*)d_out;
    if (ws_size < F_TOTAL * sizeof(float)) return;

    hipMemsetAsync(ws + F_MSET, 0, F_MSET_CNT * sizeof(float), stream);
    kW<<<1, 256, 0, stream>>>(fr2_w, fr3_w, ws);
    k0_inbn<<<P_, 256, 0, stream>>>(x, bnx_g, bnx_b, ws);
    k1_uv<<<B_, 256, 0, stream>>>(x, fr1_w, fr1_b, ws);
    k2_bn1<<<B_, 64, 0, stream>>>(ws);
    k3_fin1<<<1, 64, 0, stream>>>(fr1_g, fr1_be, ws);
    kedge<1><<<ROWS, 256, 0, stream>>>(fr2_b, fr3_b, ws);
    k5_fin2<<<1, 128, 0, stream>>>(fr2_g, fr2_be, ws);
    kedge<2><<<ROWS, 256, 0, stream>>>(fr2_b, fr3_b, ws);
    k7_fin3<<<1, 64, 0, stream>>>(fr3_g, fr3_be, ws);
    kedge<3><<<ROWS, 256, 0, stream>>>(fr2_b, fr3_b, ws);
    k_obj<64><<<ROWS / 64, 256, 0, stream>>>(ws + F_XT, ws + F_EBAR, nullptr, nullptr,
                                             fo1_w, fo1_b, ws + F_HO1, ws + F_SO1);
    k_finO<64><<<1, 64, 0, stream>>>(ws + F_SO1, fo1_g, fo1_be, ws + F_SCO1, ws + F_SHO1);
    k_obj<64><<<ROWS / 64, 256, 0, stream>>>(ws + F_HO1, nullptr, ws + F_SCO1, ws + F_SHO1,
                                             fo2_w, fo2_b, ws + F_HO2, ws + F_SO2);
    k_finO<64><<<1, 64, 0, stream>>>(ws + F_SO2, fo2_g, fo2_be, ws + F_SCO2, ws + F_SHO2);
    k_obj<32><<<ROWS / 128, 256, 0, stream>>>(ws + F_HO2, nullptr, ws + F_SCO2, ws + F_SHO2,
                                              fo3_w, fo3_b, ws + F_HO3, ws + F_SO3);
    k_finO<32><<<1, 32, 0, stream>>>(ws + F_SO3, fo3_g, fo3_be, ws + F_SCO3, ws + F_SHO3);
    k15_final<<<B_, 64, 0, stream>>>(fc_w, fc_b, ws, out);
}

// Round 3
// 277.129 us; speedup vs baseline: 2.1184x; 1.8093x over previous
//
#include <hip/hip_runtime.h>

typedef unsigned short ushortT;
typedef __attribute__((ext_vector_type(8))) short bf16x8;
typedef __attribute__((ext_vector_type(4))) float f32x4;

constexpr int B_ = 256, P_ = 32, N_ = 60;
constexpr int NE = N_ * (N_ - 1);          // 3540 edges per batch
constexpr int NETOT = B_ * NE;             // 906240 total edge rows
constexpr int ROWS = B_ * N_;              // 15360 object rows
constexpr float EPS = 1e-5f;

// ---- workspace layout (float offsets) ----
constexpr size_t F_U      = 0;                                  // ROWS*64 (b1 folded in; later bn1-folded in place)
constexpr size_t F_V      = F_U + (size_t)ROWS * 64;            // ROWS*64
constexpr size_t F_XT     = F_V + (size_t)ROWS * 64;            // ROWS*32 xbn transposed
constexpr size_t F_EBAR   = F_XT + (size_t)ROWS * 32;           // ROWS*32
constexpr size_t F_HO1    = F_EBAR + (size_t)ROWS * 32;         // ROWS*64
constexpr size_t F_HO2    = F_HO1 + (size_t)ROWS * 64;          // ROWS*64
constexpr size_t F_HO3    = F_HO2 + (size_t)ROWS * 64;          // ROWS*32
constexpr size_t F_SCALEX = F_HO3 + (size_t)ROWS * 32;          // 32
constexpr size_t F_SHIFTX = F_SCALEX + 32;                      // 32
constexpr size_t F_BN1S   = F_SHIFTX + 32;                      // B*64
constexpr size_t F_BN1Q   = F_BN1S + (size_t)B_ * 64;           // B*64
constexpr size_t F_SC1    = F_BN1Q + (size_t)B_ * 64;           // 64
constexpr size_t F_SH1    = F_SC1 + 64;
constexpr size_t F_SC2    = F_SH1 + 64;                         // 64 (scale)
constexpr size_t F_SH2    = F_SC2 + 64;                         // 64 (shift, bias folded)
constexpr size_t F_SC3    = F_SH2 + 64;                         // 32
constexpr size_t F_SH3    = F_SC3 + 32;                         // 32
constexpr size_t F_SCO1   = F_SH3 + 32;                         // 64
constexpr size_t F_SHO1   = F_SCO1 + 64;
constexpr size_t F_SCO2   = F_SHO1 + 64;
constexpr size_t F_SHO2   = F_SCO2 + 64;
constexpr size_t F_SCO3   = F_SHO2 + 64;                        // 32
constexpr size_t F_SHO3   = F_SCO3 + 32;
constexpr size_t F_W2F    = F_SHO3 + 32;                        // 2048 floats = 4096 bf16 frags
constexpr size_t F_W3F    = F_W2F + 2048;                       // 1024 floats
// zero-initialized (atomic accumulation) region:
constexpr size_t F_PART2  = F_W3F + 1024;                       // 256*128
constexpr size_t F_PART3  = F_PART2 + 256 * 128;                // 256*64
constexpr size_t F_INS    = F_PART3 + 256 * 64;                 // 64 (input-bn raw stats)
constexpr size_t F_SO1    = F_INS + 64;                         // 128
constexpr size_t F_SO2    = F_SO1 + 128;                        // 128
constexpr size_t F_SO3    = F_SO2 + 128;                        // 64
constexpr size_t F_END    = F_SO3 + 64;
constexpr size_t F_MSET     = F_PART2;
constexpr size_t F_MSET_CNT = F_END - F_PART2;
constexpr size_t F_TOTAL  = F_END;

static __device__ __forceinline__ ushortT f2bf(float f) {
    unsigned int u = __float_as_uint(f);
    u += 0x7fffu + ((u >> 16) & 1u);
    return (ushortT)(u >> 16);
}
static __device__ __forceinline__ unsigned int packbf(float lo, float hi) {
    return (unsigned int)f2bf(lo) | ((unsigned int)f2bf(hi) << 16);
}
// single-instruction packed f32->bf16 (RNE)
static __device__ __forceinline__ unsigned int cvtpk(float lo, float hi) {
    unsigned int r;
    asm("v_cvt_pk_bf16_f32 %0, %1, %2" : "=v"(r) : "v"(lo), "v"(hi));
    return r;
}

// ---- K0a: input BN raw stats (partials via atomics) ----
__global__ __launch_bounds__(256) void k0_part(const float* __restrict__ x,
                                               float* __restrict__ ws) {
    int p = blockIdx.x & 31, seg = blockIdx.x >> 5;   // 8 segs x 32 batches
    float s = 0.f, q = 0.f;
    for (int idx = threadIdx.x; idx < 32 * N_; idx += 256) {
        int bb = seg * 32 + idx / N_;
        int n = idx - (idx / N_) * N_;
        float v = x[(size_t)(bb * P_ + p) * N_ + n];
        s += v; q += v * v;
    }
    for (int o = 32; o > 0; o >>= 1) { s += __shfl_down(s, o); q += __shfl_down(q, o); }
    __shared__ float rs[4], rq[4];
    int wid = threadIdx.x >> 6, lane = threadIdx.x & 63;
    if (lane == 0) { rs[wid] = s; rq[wid] = q; }
    __syncthreads();
    if (threadIdx.x == 0) {
        s = rs[0] + rs[1] + rs[2] + rs[3];
        q = rq[0] + rq[1] + rq[2] + rq[3];
        atomicAdd(ws + F_INS + p, s);
        atomicAdd(ws + F_INS + 32 + p, q);
    }
}

// ---- K0b: finalize input BN ----
__global__ void k0b(const float* __restrict__ g, const float* __restrict__ bt,
                    float* __restrict__ ws) {
    int p = threadIdx.x;
    if (p < 32) {
        float inv = 1.f / (float)(B_ * N_);
        float mean = ws[F_INS + p] * inv;
        float var = ws[F_INS + 32 + p] * inv - mean * mean;
        float sc = g[p] * rsqrtf(var + EPS);
        ws[F_SCALEX + p] = sc;
        ws[F_SHIFTX + p] = bt[p] - mean * sc;
    }
}

// ---- KW: convert W2 (64x64), W3 (32x64) to bf16 MFMA fragment layout ----
__global__ __launch_bounds__(256) void kW(const float* __restrict__ w2,
                                          const float* __restrict__ w3,
                                          float* __restrict__ ws) {
    int t = threadIdx.x;
    ushortT* w2f = reinterpret_cast<ushortT*>(ws + F_W2F);
    ushortT* w3f = reinterpret_cast<ushortT*>(ws + F_W3F);
    for (int c = t; c < 512; c += 256) {
        int l = c & 63, s = (c >> 6) & 1, mu = c >> 7;
        int f = mu * 16 + (l & 15);
        int k0 = s * 32 + ((l >> 4) << 3);
        const float* src = w2 + (size_t)f * 64 + k0;
        unsigned int pk[4];
        #pragma unroll
        for (int q = 0; q < 4; ++q) pk[q] = packbf(src[2 * q], src[2 * q + 1]);
        *reinterpret_cast<uint4*>(&w2f[(size_t)c * 8]) = *reinterpret_cast<uint4*>(pk);
    }
    {
        int c = t;
        int l = c & 63, s = (c >> 6) & 1, mu = (c >> 7) & 1;
        int f = mu * 16 + (l & 15);
        int k0 = s * 32 + ((l >> 4) << 3);
        const float* src = w3 + (size_t)f * 64 + k0;
        unsigned int pk[4];
        #pragma unroll
        for (int q = 0; q < 4; ++q) pk[q] = packbf(src[2 * q], src[2 * q + 1]);
        *reinterpret_cast<uint4*>(&w3f[(size_t)c * 8]) = *reinterpret_cast<uint4*>(pk);
    }
}

// ---- K1: U = xbn·Wrecv^T + b1, V = xbn·Wsend^T; also write xt ----
__global__ __launch_bounds__(256) void k1_uv(const float* __restrict__ x,
                                             const float* __restrict__ w1,
                                             const float* __restrict__ b1,
                                             float* __restrict__ ws) {
    int b = blockIdx.x;
    __shared__ float xs[P_ * N_];
    __shared__ float w1t[64 * 65];
    const float* sX = ws + F_SCALEX;
    const float* tX = ws + F_SHIFTX;
    for (int idx = threadIdx.x; idx < P_ * N_; idx += 256) {
        int p = idx / N_, n = idx - (idx / N_) * N_;
        xs[idx] = sX[p] * x[(size_t)(b * P_ + p) * N_ + n] + tX[p];
    }
    for (int idx = threadIdx.x; idx < 64 * 64; idx += 256) {
        int k = idx >> 6, c = idx & 63;
        w1t[c * 65 + k] = w1[idx];
    }
    __syncthreads();
    for (int idx = threadIdx.x; idx < N_ * P_; idx += 256) {
        int n = idx / P_, p = idx - (idx / P_) * P_;
        ws[F_XT + (size_t)(b * N_ + n) * P_ + p] = xs[p * N_ + n];
    }
    const int k = threadIdx.x & 63;
    float wu[32], wv[32];
    #pragma unroll
    for (int p = 0; p < 32; ++p) {
        wu[p] = w1t[p * 65 + k];
        wv[p] = w1t[(32 + p) * 65 + k];
    }
    const float b1k = b1[k];
    for (int idx = threadIdx.x; idx < N_ * 64; idx += 256) {
        int n = idx >> 6;
        float u = b1k, v = 0.f;
        #pragma unroll
        for (int p = 0; p < 32; ++p) {
            float xv = xs[p * N_ + n];
            u += xv * wu[p];
            v += xv * wv[p];
        }
        ws[F_U + (size_t)(b * N_ + n) * 64 + k] = u;
        ws[F_V + (size_t)(b * N_ + n) * 64 + k] = v;
    }
}

// ---- K2: per-batch closed-form BN1 partial stats (raw U,V) ----
__global__ __launch_bounds__(64) void k2_bn1(float* __restrict__ ws) {
    int b = blockIdx.x, k = threadIdx.x;
    const float* Up = ws + F_U + (size_t)b * N_ * 64;
    const float* Vp = ws + F_V + (size_t)b * N_ * 64;
    float su = 0, sv = 0, suu = 0, svv = 0, suv = 0;
    for (int n = 0; n < N_; ++n) {
        float u = Up[n * 64 + k], v = Vp[n * 64 + k];
        su += u; sv += v; suu += u * u; svv += v * v; suv += u * v;
    }
    ws[F_BN1S + b * 64 + k] = 59.f * (su + sv);
    ws[F_BN1Q + b * 64 + k] = 59.f * (suu + svv) + 2.f * (su * sv - suv);
}

// ---- K3: finalize BN1 ----
__global__ __launch_bounds__(256) void k3_fin1(const float* __restrict__ g,
                                               const float* __restrict__ be,
                                               float* __restrict__ ws) {
    int k = threadIdx.x & 63, part = threadIdx.x >> 6;
    float S = 0, Q = 0;
    for (int b = part; b < B_; b += 4) {
        S += ws[F_BN1S + b * 64 + k];
        Q += ws[F_BN1Q + b * 64 + k];
    }
    __shared__ float rs[4][64], rq[4][64];
    rs[part][k] = S; rq[part][k] = Q;
    __syncthreads();
    if (threadIdx.x < 64) {
        S = rs[0][k] + rs[1][k] + rs[2][k] + rs[3][k];
        Q = rq[0][k] + rq[1][k] + rq[2][k] + rq[3][k];
        float inv = 1.f / (float)NETOT;
        float mean = S * inv;
        float var = Q * inv - mean * mean;
        float sc = g[k] * rsqrtf(var + EPS);
        ws[F_SC1 + k] = sc;
        ws[F_SH1 + k] = be[k] - mean * sc;
    }
}

// ---- K3b: fold BN1 into U,V in place: U' = sc1*U + sh1 ; V' = sc1*V ----
__global__ __launch_bounds__(256) void k3b(float* __restrict__ ws) {
    size_t gid = (size_t)blockIdx.x * 256 + threadIdx.x;    // ROWS*16 float4s
    int k4 = (int)(gid & 15) << 2;
    float4 sc = *reinterpret_cast<const float4*>(ws + F_SC1 + k4);
    float4 sh = *reinterpret_cast<const float4*>(ws + F_SH1 + k4);
    float* up = ws + F_U + gid * 4;
    float* vp = ws + F_V + gid * 4;
    float4 u = *reinterpret_cast<float4*>(up);
    float4 v = *reinterpret_cast<float4*>(vp);
    u.x = sc.x * u.x + sh.x; u.y = sc.y * u.y + sh.y;
    u.z = sc.z * u.z + sh.z; u.w = sc.w * u.w + sh.w;
    v.x *= sc.x; v.y *= sc.y; v.z *= sc.z; v.w *= sc.w;
    *reinterpret_cast<float4*>(up) = u;
    *reinterpret_cast<float4*>(vp) = v;
}

// ---- KEDGE<STAGE>: 4 blocks per batch, 15 (b,i)-groups each ----
// STAGE 1: raw h2' stats -> PART2.  STAGE 2: e2=relu(bn2), raw h3' stats -> PART3.
// STAGE 3: full recompute, bn3relu, segment-sum -> EBAR.
template <int STAGE>
__global__ __launch_bounds__(256, 4) void kedge(float* __restrict__ ws) {
    __shared__ __align__(16) float sV[60 * 68];
    __shared__ __align__(16) float sU[15 * 68];
    __shared__ __align__(16) ushortT e1f[512 * 8];
    __shared__ __align__(16) ushortT e2f[(STAGE >= 2) ? 512 * 8 : 16];
    __shared__ float red[4][64];
    __shared__ float sBN[(STAGE >= 2) ? 192 : 4];

    const int blk = blockIdx.x;
    const int b = blk >> 2, i0 = (blk & 3) * 15;
    const int t = threadIdx.x;
    const int w = t >> 6, lane = t & 63;
    const int gq = lane >> 4, ln = lane & 15;

    // load V' (full batch), U' (this block's 15 rows)
    {
        const float* Vg = ws + F_V + (size_t)b * N_ * 64;
        const float* Ug = ws + F_U + (size_t)(b * N_ + i0) * 64;
        for (int idx = t; idx < 960; idx += 256) {
            int r = idx >> 4, c = (idx & 15) << 2;
            *reinterpret_cast<float4*>(&sV[r * 68 + c]) =
                *reinterpret_cast<const float4*>(Vg + (size_t)r * 64 + c);
        }
        for (int idx = t; idx < 240; idx += 256) {
            int r = idx >> 4, c = (idx & 15) << 2;
            *reinterpret_cast<float4*>(&sU[r * 68 + c]) =
                *reinterpret_cast<const float4*>(Ug + (size_t)r * 64 + c);
        }
        if constexpr (STAGE == 2) {
            if (t < 128) sBN[t] = ws[F_SC2 + t];
        } else if constexpr (STAGE == 3) {
            if (t < 192) sBN[t] = (t < 128) ? ws[F_SC2 + t] : ws[F_SC3 + (t - 128)];
        }
    }

    const bf16x8* __restrict__ w2fr = reinterpret_cast<const bf16x8*>(ws + F_W2F);
    const bf16x8* __restrict__ w3fr = reinterpret_cast<const bf16x8*>(ws + F_W3F);
    const bf16x8* e1c = reinterpret_cast<const bf16x8*>(e1f);
    const bf16x8* e2c = reinterpret_cast<const bf16x8*>(e2f);
    const f32x4 zero = {0.f, 0.f, 0.f, 0.f};

    // preload weight fragments into registers
    bf16x8 aw[8], cw[4];
    if constexpr (STAGE == 1) {
        aw[0] = w2fr[(w * 2) * 64 + lane];
        aw[1] = w2fr[(w * 2 + 1) * 64 + lane];
    } else {
        #pragma unroll
        for (int q = 0; q < 8; ++q) aw[q] = w2fr[q * 64 + lane];
        #pragma unroll
        for (int q = 0; q < 4; ++q) cw[q] = w3fr[q * 64 + lane];
    }

    float st0 = 0.f, st1 = 0.f, st2 = 0.f, st3 = 0.f;   // persistent stats

    for (int gi = 0; gi < 15; ++gi) {
        const int i = i0 + gi;
        __syncthreads();
        // ---- build e1 fragments from LDS U',V' ----
        #pragma unroll
        for (int c2 = 0; c2 < 2; ++c2) {
            int c = t + (c2 << 8);
            int l = c & 63, s = (c >> 6) & 1, m = c >> 7;
            int e_loc = (m << 4) + (l & 15);
            int k0 = (s << 5) + ((l >> 4) << 3);
            uint4 outp = {0u, 0u, 0u, 0u};
            if (e_loc < 59) {
                int j = e_loc + (e_loc >= i ? 1 : 0);
                const float* up = &sU[gi * 68 + k0];
                const float* vp = &sV[j * 68 + k0];
                float4 ua = *reinterpret_cast<const float4*>(up);
                float4 ub = *reinterpret_cast<const float4*>(up + 4);
                float4 va = *reinterpret_cast<const float4*>(vp);
                float4 vb = *reinterpret_cast<const float4*>(vp + 4);
                outp.x = cvtpk(fmaxf(0.f, ua.x + va.x), fmaxf(0.f, ua.y + va.y));
                outp.y = cvtpk(fmaxf(0.f, ua.z + va.z), fmaxf(0.f, ua.w + va.w));
                outp.z = cvtpk(fmaxf(0.f, ub.x + vb.x), fmaxf(0.f, ub.y + vb.y));
                outp.w = cvtpk(fmaxf(0.f, ub.z + vb.z), fmaxf(0.f, ub.w + vb.w));
            }
            *reinterpret_cast<uint4*>(&e1f[(size_t)c * 8]) = outp;
        }
        __syncthreads();

        if constexpr (STAGE == 1) {
            // h2' = e1 · W2^T ; wave w = feature tile; stats only
            f32x4 acc[4] = {zero, zero, zero, zero};
            #pragma unroll
            for (int s = 0; s < 2; ++s)
                #pragma unroll
                for (int m = 0; m < 4; ++m)
                    acc[m] = __builtin_amdgcn_mfma_f32_16x16x32_bf16(
                        e1c[(m * 2 + s) * 64 + lane], aw[s], acc[m], 0, 0, 0);
            #pragma unroll
            for (int m = 0; m < 4; ++m)
                #pragma unroll
                for (int r = 0; r < 4; ++r) {
                    float h = acc[m][r];
                    st0 += h; st1 += h * h;
                }
        } else {
            // h2'^T = W2 · e1^T ; wave w = edge tile (cols)
            f32x4 acc[4] = {zero, zero, zero, zero};
            #pragma unroll
            for (int s = 0; s < 2; ++s) {
                bf16x8 be = e1c[(w * 2 + s) * 64 + lane];
                #pragma unroll
                for (int mu = 0; mu < 4; ++mu)
                    acc[mu] = __builtin_amdgcn_mfma_f32_16x16x32_bf16(
                        aw[mu * 2 + s], be, acc[mu], 0, 0, 0);
            }
            // e2 = relu(sc2*h2' + sh2eff), zero pads, scatter to e2 fragments
            const bool edge_ok = (w * 16 + ln) < 59;
            #pragma unroll
            for (int mu = 0; mu < 4; ++mu) {
                int fb = mu * 16 + gq * 4;
                float4 s2  = *reinterpret_cast<const float4*>(&sBN[fb]);
                float4 h2s = *reinterpret_cast<const float4*>(&sBN[64 + fb]);
                float e0 = fmaxf(0.f, s2.x * acc[mu][0] + h2s.x);
                float e1v = fmaxf(0.f, s2.y * acc[mu][1] + h2s.y);
                float e2v = fmaxf(0.f, s2.z * acc[mu][2] + h2s.z);
                float e3v = fmaxf(0.f, s2.w * acc[mu][3] + h2s.w);
                unsigned int pk0 = cvtpk(e0, e1v), pk1 = cvtpk(e2v, e3v);
                if (!edge_ok) { pk0 = 0u; pk1 = 0u; }
                int sp = mu >> 1;
                int lp = ln + ((mu & 1) << 5) + ((gq >> 1) << 4);
                int base = ((w * 2 + sp) * 64 + lp) * 8 + ((gq & 1) << 2);
                uint2 pr; pr.x = pk0; pr.y = pk1;
                *reinterpret_cast<uint2*>(&e2f[base]) = pr;
            }
            __syncthreads();
            // h3' = e2 · W3^T ; wave w = its own edge tile
            f32x4 acc3[2] = {zero, zero};
            #pragma unroll
            for (int s = 0; s < 2; ++s) {
                bf16x8 ae = e2c[(w * 2 + s) * 64 + lane];
                #pragma unroll
                for (int nv = 0; nv < 2; ++nv)
                    acc3[nv] = __builtin_amdgcn_mfma_f32_16x16x32_bf16(
                        ae, cw[nv * 2 + s], acc3[nv], 0, 0, 0);
            }
            if constexpr (STAGE == 2) {
                #pragma unroll
                for (int r = 0; r < 4; ++r) {
                    float h0 = acc3[0][r], h1 = acc3[1][r];
                    st0 += h0; st1 += h0 * h0;
                    st2 += h1; st3 += h1 * h1;
                }
            } else {
                float s30 = sBN[128 + ln], s31 = sBN[128 + 16 + ln];
                float t30 = sBN[160 + ln], t31 = sBN[160 + 16 + ln];
                float es0 = 0.f, es1 = 0.f;
                #pragma unroll
                for (int r = 0; r < 4; ++r) {
                    if (w * 16 + gq * 4 + r < 59) {
                        es0 += fmaxf(0.f, s30 * acc3[0][r] + t30);
                        es1 += fmaxf(0.f, s31 * acc3[1][r] + t31);
                    }
                }
                es0 += __shfl_xor(es0, 16); es1 += __shfl_xor(es1, 16);
                es0 += __shfl_xor(es0, 32); es1 += __shfl_xor(es1, 32);
                if (lane < 16) { red[w][ln] = es0; red[w][16 + ln] = es1; }
                __syncthreads();
                if (t < 32)
                    ws[F_EBAR + (size_t)(b * N_ + i) * 32 + t] =
                        red[0][t] + red[1][t] + red[2][t] + red[3][t];
            }
        }
    }

    // ---- epilogue: reduce persistent stats, one atomic round per block ----
    if constexpr (STAGE == 1) {
        st0 += __shfl_xor(st0, 16); st1 += __shfl_xor(st1, 16);
        st0 += __shfl_xor(st0, 32); st1 += __shfl_xor(st1, 32);
        if (lane < 16) {
            float* pb = ws + F_PART2 + (size_t)(blk & 255) * 128;
            atomicAdd(pb + w * 16 + lane, st0);
            atomicAdd(pb + 64 + w * 16 + lane, st1);
        }
    } else if constexpr (STAGE == 2) {
        st0 += __shfl_xor(st0, 16); st1 += __shfl_xor(st1, 16);
        st2 += __shfl_xor(st2, 16); st3 += __shfl_xor(st3, 16);
        st0 += __shfl_xor(st0, 32); st1 += __shfl_xor(st1, 32);
        st2 += __shfl_xor(st2, 32); st3 += __shfl_xor(st3, 32);
        __syncthreads();
        if (lane < 16) {
            red[w][ln] = st0; red[w][16 + ln] = st2;
            red[w][32 + ln] = st1; red[w][48 + ln] = st3;
        }
        __syncthreads();
        if (t < 64) {
            float tot = red[0][t] + red[1][t] + red[2][t] + red[3][t];
            atomicAdd(ws + F_PART3 + (size_t)(blk & 255) * 64 + t, tot);
        }
    }
}

// ---- K5: finalize BN2 (raw sums; bias-folded shift) ----
__global__ __launch_bounds__(512) void k5_fin2(const float* __restrict__ g,
                                               const float* __restrict__ be,
                                               float* __restrict__ ws) {
    int c = threadIdx.x & 127, part = threadIdx.x >> 7;
    float acc = 0.f;
    for (int r = part * 64; r < part * 64 + 64; ++r)
        acc += ws[F_PART2 + (size_t)r * 128 + c];
    __shared__ float red[4][128];
    red[part][c] = acc;
    __syncthreads();
    if (threadIdx.x < 64) {
        int s = threadIdx.x;
        float S = red[0][s] + red[1][s] + red[2][s] + red[3][s];
        float Q = red[0][64 + s] + red[1][64 + s] + red[2][64 + s] + red[3][64 + s];
        float inv = 1.f / (float)NETOT;
        float m = S * inv;
        float var = Q * inv - m * m;
        float sc = g[s] * rsqrtf(var + EPS);
        ws[F_SC2 + s] = sc;
        ws[F_SH2 + s] = be[s] - m * sc;
    }
}

// ---- K7: finalize BN3 ----
__global__ __launch_bounds__(256) void k7_fin3(const float* __restrict__ g,
                                               const float* __restrict__ be,
                                               float* __restrict__ ws) {
    int c = threadIdx.x & 63, part = threadIdx.x >> 6;
    float acc = 0.f;
    for (int r = part * 64; r < part * 64 + 64; ++r)
        acc += ws[F_PART3 + (size_t)r * 64 + c];
    __shared__ float red[4][64];
    red[part][c] = acc;
    __syncthreads();
    if (threadIdx.x < 32) {
        int s = threadIdx.x;
        float S = red[0][s] + red[1][s] + red[2][s] + red[3][s];
        float Q = red[0][32 + s] + red[1][32 + s] + red[2][32 + s] + red[3][32 + s];
        float inv = 1.f / (float)NETOT;
        float m = S * inv;
        float var = Q * inv - m * m;
        float sc = g[s] * rsqrtf(var + EPS);
        ws[F_SC3 + s] = sc;
        ws[F_SH3 + s] = be[s] - m * sc;
    }
}

// ---- object-path linear (+optional input bn-relu), stats accumulated ----
template <int OUT>
__global__ __launch_bounds__(256) void k_obj(const float* __restrict__ srcA,
                                             const float* __restrict__ srcB,
                                             const float* __restrict__ actSc,
                                             const float* __restrict__ actSh,
                                             const float* __restrict__ W,
                                             const float* __restrict__ bias,
                                             float* __restrict__ outp,
                                             float* __restrict__ statBuf) {
    constexpr int TRN = (OUT == 64) ? 16 : 32;
    constexpr int RB = 4 * TRN;
    constexpr int SP = RB + 4;
    constexpr int WP = OUT + 4;
    __shared__ __align__(16) float sinT[64 * SP];
    __shared__ __align__(16) float swt[64 * WP];
    const int t = threadIdx.x;
    const int row0 = blockIdx.x * RB;
    for (int idx = t; idx < RB * 64; idx += 256) {
        int r = idx % RB, k = idx / RB;
        float v;
        if (srcB) {
            v = (k < 32) ? srcA[(size_t)(row0 + r) * 32 + k]
                         : srcB[(size_t)(row0 + r) * 32 + (k - 32)];
        } else {
            v = srcA[(size_t)(row0 + r) * 64 + k];
        }
        if (actSc) v = fmaxf(0.f, actSc[k] * v + actSh[k]);
        sinT[k * SP + r] = v;
    }
    for (int idx = t; idx < OUT * 64; idx += 256) {
        int o = idx >> 6, k = idx & 63;
        swt[k * WP + o] = W[idx];
    }
    __syncthreads();
    const int tr = t % TRN, to = t / TRN;
    const int r0 = tr * 4, o0 = to * 4;
    float acc[4][4];
    #pragma unroll
    for (int a = 0; a < 4; ++a)
        #pragma unroll
        for (int c = 0; c < 4; ++c) acc[a][c] = 0.f;
    #pragma unroll 8
    for (int k = 0; k < 64; ++k) {
        float4 a4 = *reinterpret_cast<const float4*>(sinT + k * SP + r0);
        float4 w4 = *reinterpret_cast<const float4*>(swt + k * WP + o0);
        float av[4] = {a4.x, a4.y, a4.z, a4.w};
        float wv[4] = {w4.x, w4.y, w4.z, w4.w};
        #pragma unroll
        for (int a = 0; a < 4; ++a)
            #pragma unroll
            for (int c = 0; c < 4; ++c) acc[a][c] += av[a] * wv[c];
    }
    float bv[4];
    #pragma unroll
    for (int c = 0; c < 4; ++c) bv[c] = bias[o0 + c];
    float lsum[4] = {0.f, 0.f, 0.f, 0.f}, lsq[4] = {0.f, 0.f, 0.f, 0.f};
    #pragma unroll
    for (int a = 0; a < 4; ++a) {
        float4 res;
        float rv[4];
        #pragma unroll
        for (int c = 0; c < 4; ++c) {
            rv[c] = acc[a][c] + bv[c];
            lsum[c] += rv[c]; lsq[c] += rv[c] * rv[c];
        }
        res.x = rv[0]; res.y = rv[1]; res.z = rv[2]; res.w = rv[3];
        *reinterpret_cast<float4*>(outp + (size_t)(row0 + r0 + a) * OUT + o0) = res;
    }
    #pragma unroll
    for (int o = TRN / 2; o >= 1; o >>= 1) {
        #pragma unroll
        for (int c = 0; c < 4; ++c) {
            lsum[c] += __shfl_down(lsum[c], o, TRN);
            lsq[c]  += __shfl_down(lsq[c], o, TRN);
        }
    }
    if (tr == 0) {
        #pragma unroll
        for (int c = 0; c < 4; ++c) {
            atomicAdd(statBuf + o0 + c, lsum[c]);
            atomicAdd(statBuf + OUT + o0 + c, lsq[c]);
        }
    }
}

template <int OUTK>
__global__ void k_finO(const float* __restrict__ statBuf, const float* __restrict__ g,
                       const float* __restrict__ be, float* __restrict__ scO,
                       float* __restrict__ shO) {
    int k = threadIdx.x;
    if (k < OUTK) {
        float inv = 1.f / (float)ROWS;
        float mean = statBuf[k] * inv;
        float var = statBuf[OUTK + k] * inv - mean * mean;
        float sc = g[k] * rsqrtf(var + EPS);
        scO[k] = sc;
        shO[k] = be[k] - mean * sc;
    }
}

// ---- K15: relu(bn(ho3)), pool over n, fc ----
__global__ __launch_bounds__(64) void k15_final(const float* __restrict__ fcw,
                                                const float* __restrict__ fcb,
                                                float* __restrict__ ws,
                                                float* __restrict__ out) {
    int b = blockIdx.x, t = threadIdx.x;
    int f = t & 31, h = t >> 5;
    float sc = ws[F_SCO3 + f], sh = ws[F_SHO3 + f];
    float acc = 0.f;
    for (int n = h; n < N_; n += 2) {
        float v = ws[F_HO3 + (size_t)(b * N_ + n) * 32 + f];
        acc += fmaxf(0.f, sc * v + sh);
    }
    acc += __shfl_down(acc, 32);
    float p0 = acc * fcw[f];
    float p1 = acc * fcw[32 + f];
    #pragma unroll
    for (int o = 16; o >= 1; o >>= 1) {
        p0 += __shfl_xor(p0, o);
        p1 += __shfl_xor(p1, o);
    }
    if (t == 0) {
        out[b * 2 + 0] = p0 + fcb[0];
        out[b * 2 + 1] = p1 + fcb[1];
    }
}

extern "C" void kernel_launch(void* const* d_in, const int* in_sizes, int n_in,
                              void* d_out, int out_size, void* d_ws, size_t ws_size,
                              hipStream_t stream) {
    const float* x      = (const float*)d_in[0];
    const float* bnx_g  = (const float*)d_in[1];
    const float* bnx_b  = (const float*)d_in[2];
    const float* fr1_w  = (const float*)d_in[3];
    const float* fr1_b  = (const float*)d_in[4];
    const float* fr1_g  = (const float*)d_in[5];
    const float* fr1_be = (const float*)d_in[6];
    const float* fr2_w  = (const float*)d_in[7];
    const float* fr2_g  = (const float*)d_in[9];
    const float* fr2_be = (const float*)d_in[10];
    const float* fr3_w  = (const float*)d_in[11];
    const float* fr3_g  = (const float*)d_in[13];
    const float* fr3_be = (const float*)d_in[14];
    const float* fo1_w  = (const float*)d_in[15];
    const float* fo1_b  = (const float*)d_in[16];
    const float* fo1_g  = (const float*)d_in[17];
    const float* fo1_be = (const float*)d_in[18];
    const float* fo2_w  = (const float*)d_in[19];
    const float* fo2_b  = (const float*)d_in[20];
    const float* fo2_g  = (const float*)d_in[21];
    const float* fo2_be = (const float*)d_in[22];
    const float* fo3_w  = (const float*)d_in[23];
    const float* fo3_b  = (const float*)d_in[24];
    const float* fo3_g  = (const float*)d_in[25];
    const float* fo3_be = (const float*)d_in[26];
    const float* fc_w   = (const float*)d_in[27];
    const float* fc_b   = (const float*)d_in[28];

    float* ws = (float*)d_ws;
    float* out = (float*)d_out;
    if (ws_size < F_TOTAL * sizeof(float)) return;

    hipMemsetAsync(ws + F_MSET, 0, F_MSET_CNT * sizeof(float), stream);
    kW<<<1, 256, 0, stream>>>(fr2_w, fr3_w, ws);
    k0_part<<<256, 256, 0, stream>>>(x, ws);
    k0b<<<1, 32, 0, stream>>>(bnx_g, bnx_b, ws);
    k1_uv<<<B_, 256, 0, stream>>>(x, fr1_w, fr1_b, ws);
    k2_bn1<<<B_, 64, 0, stream>>>(ws);
    k3_fin1<<<1, 256, 0, stream>>>(fr1_g, fr1_be, ws);
    k3b<<<ROWS * 16 / 256, 256, 0, stream>>>(ws);
    kedge<1><<<B_ * 4, 256, 0, stream>>>(ws);
    k5_fin2<<<1, 512, 0, stream>>>(fr2_g, fr2_be, ws);
    kedge<2><<<B_ * 4, 256, 0, stream>>>(ws);
    k7_fin3<<<1, 256, 0, stream>>>(fr3_g, fr3_be, ws);
    kedge<3><<<B_ * 4, 256, 0, stream>>>(ws);
    k_obj<64><<<ROWS / 64, 256, 0, stream>>>(ws + F_XT, ws + F_EBAR, nullptr, nullptr,
                                             fo1_w, fo1_b, ws + F_HO1, ws + F_SO1);
    k_finO<64><<<1, 64, 0, stream>>>(ws + F_SO1, fo1_g, fo1_be, ws + F_SCO1, ws + F_SHO1);
    k_obj<64><<<ROWS / 64, 256, 0, stream>>>(ws + F_HO1, nullptr, ws + F_SCO1, ws + F_SHO1,
                                             fo2_w, fo2_b, ws + F_HO2, ws + F_SO2);
    k_finO<64><<<1, 64, 0, stream>>>(ws + F_SO2, fo2_g, fo2_be, ws + F_SCO2, ws + F_SHO2);
    k_obj<32><<<ROWS / 128, 256, 0, stream>>>(ws + F_HO2, nullptr, ws + F_SCO2, ws + F_SHO2,
                                              fo3_w, fo3_b, ws + F_HO3, ws + F_SO3);
    k_finO<32><<<1, 32, 0, stream>>>(ws + F_SO3, fo3_g, fo3_be, ws + F_SCO3, ws + F_SHO3);
    k15_final<<<B_, 64, 0, stream>>>(fc_w, fc_b, ws, out);
}